// Round 4
// baseline (570.988 us; speedup 1.0000x reference)
//
#include <hip/hip_runtime.h>
#include <math.h>

typedef __bf16 bf16x8 __attribute__((ext_vector_type(8)));
typedef float f32x4 __attribute__((ext_vector_type(4)));

#define DDIM 1024
#define HDIM 4096
#define NE 8
#define TT 4096
#define CAP 8192

static const size_t OFF_CTRL   = 0;
static const size_t OFF_ROWMAP = 256;
static const size_t OFF_ROWPOS = OFF_ROWMAP + (size_t)CAP * 4;
static const size_t OFF_TOKE   = OFF_ROWPOS + (size_t)TT * 2 * 4;
static const size_t OFF_TOKW   = OFF_TOKE + (size_t)TT * 2 * 4;
static const size_t OFF_XB     = OFF_TOKW + (size_t)TT * 2 * 4;
static const size_t OFF_W1T    = OFF_XB + (size_t)TT * DDIM * 2;
static const size_t OFF_W2T    = OFF_W1T + (size_t)NE * HDIM * DDIM * 2;
static const size_t OFF_H      = OFF_W2T + (size_t)NE * DDIM * HDIM * 2;
static const size_t OFF_PO     = OFF_H + (size_t)CAP * HDIM * 2;
static const size_t WS_NEED    = OFF_PO + (size_t)CAP * DDIM * 4;

__device__ __forceinline__ unsigned short f2bf(float f) {
  unsigned int u = __builtin_bit_cast(unsigned int, f);
  u = (u + 0x7FFFu + ((u >> 16) & 1u)) >> 16;
  return (unsigned short)u;
}

__device__ __forceinline__ void async16(void* lds, const void* g) {
  __builtin_amdgcn_global_load_lds(
      (__attribute__((address_space(1))) void*)g,
      (__attribute__((address_space(3))) void*)lds, 16, 0, 0);
}

__device__ __forceinline__ float gelu_exact(float v) {
  return 0.5f * v * (1.0f + erff(v * 0.70710678118654752f));
}

// ---------------- router ----------------
__global__ __launch_bounds__(256) void router_k(
    const float* __restrict__ x, const float* __restrict__ Wr, const float* __restrict__ br,
    unsigned short* __restrict__ xb, int* __restrict__ ctrl,
    int* __restrict__ toke, float* __restrict__ tokw) {
  int tid = threadIdx.x, lane = tid & 63, wid = tid >> 6;
  int t = blockIdx.x * 4 + wid;
  const float* xr = x + (size_t)t * DDIM;
  float acc[NE];
#pragma unroll
  for (int e = 0; e < NE; ++e) acc[e] = 0.f;
#pragma unroll
  for (int it = 0; it < DDIM / 64; ++it) {
    int d = lane + it * 64;
    float xv = xr[d];
    xb[(size_t)t * DDIM + d] = f2bf(xv);
    const float4* w4 = (const float4*)(Wr + (size_t)d * NE);
    float4 wa = w4[0], wb = w4[1];
    acc[0] += xv * wa.x; acc[1] += xv * wa.y; acc[2] += xv * wa.z; acc[3] += xv * wa.w;
    acc[4] += xv * wb.x; acc[5] += xv * wb.y; acc[6] += xv * wb.z; acc[7] += xv * wb.w;
  }
#pragma unroll
  for (int e = 0; e < NE; ++e) {
#pragma unroll
    for (int s = 32; s > 0; s >>= 1) acc[e] += __shfl_xor(acc[e], s, 64);
  }
  if (lane == 0) {
    float l[NE];
#pragma unroll
    for (int e = 0; e < NE; ++e) l[e] = acc[e] + br[e];
    int i0 = 0; float m0 = l[0];
#pragma unroll
    for (int e = 1; e < NE; ++e) if (l[e] > m0) { m0 = l[e]; i0 = e; }
    int i1 = -1; float m1 = -3.4e38f;
#pragma unroll
    for (int e = 0; e < NE; ++e) if (e != i0 && l[e] > m1) { m1 = l[e]; i1 = e; }
    float e1 = expf(m1 - m0);
    float s = 1.f + e1;
    toke[2 * t] = i0;  toke[2 * t + 1] = i1;
    tokw[2 * t] = 1.f / s;  tokw[2 * t + 1] = e1 / s;
    atomicAdd(&ctrl[i0], 1);
    atomicAdd(&ctrl[i1], 1);
  }
}

__global__ void scan_k(int* ctrl) {
  if (threadIdx.x == 0) {
    int off = 0;
    for (int e = 0; e < NE; ++e) {
      ctrl[8 + e] = off;
      ctrl[20 + e] = off;
      off += ctrl[e];
    }
    ctrl[16] = off;
  }
}

__global__ __launch_bounds__(256) void assign_k(
    const int* __restrict__ toke, int* ctrl,
    int* __restrict__ rowmap, int* __restrict__ rowpos) {
  int t = blockIdx.x * 256 + threadIdx.x;
#pragma unroll
  for (int k = 0; k < 2; ++k) {
    int e = toke[2 * t + k];
    int r = atomicAdd(&ctrl[20 + e], 1);
    rowmap[r] = t;
    rowpos[2 * t + k] = r;
  }
}

// ---------------- fp32 -> bf16 transpose convert ----------------
__global__ __launch_bounds__(256) void convT_k(
    const float* __restrict__ src, unsigned short* __restrict__ dst, int K_, int N_) {
  __shared__ unsigned int lds32[64][33];
  int e = blockIdx.z;
  int kb = blockIdx.y << 6, nb = blockIdx.x << 6;
  int t = threadIdx.x;
  const float* s = src + (size_t)e * K_ * N_ + (size_t)kb * N_ + nb;
  int n0 = (t & 15) << 2;
#pragma unroll
  for (int i = 0; i < 2; ++i) {
    int k2 = (i << 4) + (t >> 4);
    float4 a = *(const float4*)(s + (size_t)(2 * k2) * N_ + n0);
    float4 b = *(const float4*)(s + (size_t)(2 * k2 + 1) * N_ + n0);
    lds32[n0 + 0][k2] = (unsigned)f2bf(a.x) | ((unsigned)f2bf(b.x) << 16);
    lds32[n0 + 1][k2] = (unsigned)f2bf(a.y) | ((unsigned)f2bf(b.y) << 16);
    lds32[n0 + 2][k2] = (unsigned)f2bf(a.z) | ((unsigned)f2bf(b.z) << 16);
    lds32[n0 + 3][k2] = (unsigned)f2bf(a.w) | ((unsigned)f2bf(b.w) << 16);
  }
  __syncthreads();
  unsigned short* dp = dst + (size_t)e * (size_t)N_ * K_ + (size_t)nb * K_ + kb;
  int n = t >> 2, c = t & 3;
  uint4 v0, v1;
  v0.x = lds32[n][(c << 2) + 0]; v0.y = lds32[n][(c << 2) + 1];
  v0.z = lds32[n][(c << 2) + 2]; v0.w = lds32[n][(c << 2) + 3];
  int c4 = (c + 4) << 2;
  v1.x = lds32[n][c4 + 0]; v1.y = lds32[n][c4 + 1];
  v1.z = lds32[n][c4 + 2]; v1.w = lds32[n][c4 + 3];
  *(uint4*)(dp + (size_t)n * K_ + (c << 3)) = v0;
  *(uint4*)(dp + (size_t)n * K_ + ((c + 4) << 3)) = v1;
}

// ---------------- pipelined 256x256 grouped GEMM (4 phases/K-tile, counted vmcnt) ----------------
// Slots: per tensor 4 x [256 rows][32 k] bf16 (16 KB), ring over (2*tile+khalf)&3.
// Swizzle: k-chunk (8 elems) XOR'd with (row>>1)&3; applied on global source AND ds_read (involution).
template <int KSTRIDE, int KLEN, int NTOT, bool GATHER, bool DOGELU, bool KSPLIT2>
__global__ __launch_bounds__(512, 2) void gemm_k(
    const unsigned short* __restrict__ A, const unsigned short* __restrict__ Bt,
    const int* __restrict__ ctrl, const int* __restrict__ rowmap,
    const float* __restrict__ bias,
    unsigned short* __restrict__ outb, float* __restrict__ outf0, float* __restrict__ outf1) {
  __shared__ __align__(16) unsigned short AL[4][256 * 32];
  __shared__ __align__(16) unsigned short BL[4][256 * 32];
  int zz = blockIdx.z;
  int e = KSPLIT2 ? (zz & 7) : zz;
  int ks = KSPLIT2 ? (zz >> 3) : 0;
  int off0 = ctrl[8 + e], off1 = ctrl[8 + e + 1];
  int row0 = off0 + (blockIdx.y << 8);
  if (row0 >= off1) return;
  int col0 = blockIdx.x << 8;
  int tid = threadIdx.x, lane = tid & 63, wid = tid >> 6;
  int wm = wid >> 2, wn = wid & 3;
  int kbeg = KSPLIT2 ? ks * KLEN : 0;

  const unsigned short* As[2];
  const unsigned short* Bs[2];
#pragma unroll
  for (int u = 0; u < 2; ++u) {
    int r = u * 128 + (tid >> 2);                       // dest row in slot
    int kc = (((tid & 3) ^ ((r >> 1) & 3)) << 3);       // inverse-swizzled k-chunk
    int ar = row0 + r; if (ar > off1 - 1) ar = off1 - 1;
    size_t arow = GATHER ? (size_t)rowmap[ar] : (size_t)ar;
    As[u] = A + arow * KSTRIDE + kbeg + kc;
    Bs[u] = Bt + ((size_t)e * NTOT + col0 + r) * KSTRIDE + kbeg + kc;
  }

  int offA[8], offB[4];
#pragma unroll
  for (int mf = 0; mf < 8; ++mf) {
    int r = (wm << 7) + (mf << 4) + (lane & 15);
    offA[mf] = (r << 5) + (((lane >> 4) ^ ((r >> 1) & 3)) << 3);
  }
#pragma unroll
  for (int nf = 0; nf < 4; ++nf) {
    int r = (wn << 6) + (nf << 4) + (lane & 15);
    offB[nf] = (r << 5) + (((lane >> 4) ^ ((r >> 1) & 3)) << 3);
  }

  f32x4 acc[8][4];
#pragma unroll
  for (int m = 0; m < 8; ++m)
#pragma unroll
    for (int n = 0; n < 4; ++n) acc[m][n] = (f32x4){0.f, 0.f, 0.f, 0.f};

#define STAGE_A(T, H)                                                         \
  { int s_ = (2 * (T) + (H)) & 3;                                             \
    async16((char*)AL[s_] + (tid << 4), As[0] + (T) * 64 + (H) * 32);         \
    async16((char*)AL[s_] + 8192 + (tid << 4), As[1] + (T) * 64 + (H) * 32); }
#define STAGE_B(T, H)                                                         \
  { int s_ = (2 * (T) + (H)) & 3;                                             \
    async16((char*)BL[s_] + (tid << 4), Bs[0] + (T) * 64 + (H) * 32);         \
    async16((char*)BL[s_] + 8192 + (tid << 4), Bs[1] + (T) * 64 + (H) * 32); }
#define LDA4(S, MH)                                                           \
  _Pragma("unroll") for (int j_ = 0; j_ < 4; ++j_)                            \
      af[j_] = *(const bf16x8*)&AL[S][offA[(MH) * 4 + j_]];
#define LDB4(S)                                                               \
  _Pragma("unroll") for (int n_ = 0; n_ < 4; ++n_)                            \
      bfr[n_] = *(const bf16x8*)&BL[S][offB[n_]];
#define MFMA16(MB)                                                            \
  __builtin_amdgcn_s_setprio(1);                                              \
  _Pragma("unroll") for (int j_ = 0; j_ < 4; ++j_)                            \
    _Pragma("unroll") for (int n_ = 0; n_ < 4; ++n_)                          \
      acc[(MB) + j_][n_] = __builtin_amdgcn_mfma_f32_16x16x32_bf16(           \
          af[j_], bfr[n_], acc[(MB) + j_][n_], 0, 0, 0);                      \
  __builtin_amdgcn_s_setprio(0);
#define BAR() __builtin_amdgcn_s_barrier()
#define VMW(N) asm volatile("s_waitcnt vmcnt(" #N ")" ::: "memory")

  // TILE: 4 phases. Stage stream: P1:A.kh1(T+1) P2:B.kh1(T+1) P3:A.kh0(T+2) P4:B.kh0(T+2).
  // vmcnt(4) at P4 leaves exactly the two T+2 halves in flight; tile T+1 fully landed.
#define TILE(T, DOS1, DOS2, DOVM0)                                            \
  {                                                                           \
    int s0_ = (2 * (T)) & 3, s1_ = s0_ + 1;                                   \
    bf16x8 af[4], bfr[4];                                                     \
    LDA4(s0_, 0); LDB4(s0_);                                                  \
    if (DOS1) STAGE_A((T) + 1, 1);                                            \
    BAR(); MFMA16(0); BAR();                                                  \
    LDA4(s0_, 1);                                                             \
    if (DOS1) STAGE_B((T) + 1, 1);                                            \
    BAR(); MFMA16(4); BAR();                                                  \
    LDA4(s1_, 0); LDB4(s1_);                                                  \
    if (DOS2) STAGE_A((T) + 2, 0);                                            \
    BAR(); MFMA16(0); BAR();                                                  \
    LDA4(s1_, 1);                                                             \
    if (DOS2) STAGE_B((T) + 2, 0);                                            \
    if (DOS2) { VMW(4); } else if (DOVM0) { VMW(0); }                         \
    BAR(); MFMA16(4); BAR();                                                  \
  }

  const int NT = KLEN / 64;
  // prologue: T0 all 4 halves + T1 kh0 pair; land T0, keep T1.kh0 in flight
  STAGE_A(0, 0); STAGE_B(0, 0); STAGE_A(0, 1); STAGE_B(0, 1);
  STAGE_A(1, 0); STAGE_B(1, 0);
  VMW(4);
  BAR();
  for (int t = 0; t < NT - 2; ++t) TILE(t, 1, 1, 0);
  TILE(NT - 2, 1, 0, 1);
  TILE(NT - 1, 0, 0, 0);

#undef TILE
#undef VMW
#undef BAR
#undef MFMA16
#undef LDB4
#undef LDA4
#undef STAGE_B
#undef STAGE_A

  float* outf = (KSPLIT2 && ks) ? outf1 : outf0;
  int r_b = (lane >> 4) << 2;
  int c_b = lane & 15;
#pragma unroll
  for (int n = 0; n < 4; ++n) {
    int col = col0 + (wn << 6) + (n << 4) + c_b;
    float bv = (KSPLIT2 && ks) ? 0.f : bias[e * NTOT + col];
#pragma unroll
    for (int m = 0; m < 8; ++m) {
#pragma unroll
      for (int r = 0; r < 4; ++r) {
        int row = row0 + (wm << 7) + (m << 4) + r_b + r;
        if (row < off1) {
          float v = acc[m][n][r] + bv;
          if (DOGELU) {
            outb[(size_t)row * NTOT + col] = f2bf(gelu_exact(v));
          } else {
            outf[(size_t)row * NTOT + col] = v;
          }
        }
      }
    }
  }
}

// ---------------- gather ----------------
__global__ __launch_bounds__(256) void gather_k(
    const float* __restrict__ p0, const float* __restrict__ p1,
    const int* __restrict__ rowpos, const float* __restrict__ tokw,
    float* __restrict__ out) {
  int t = blockIdx.x, d = threadIdx.x << 2;
  int r0 = rowpos[2 * t], r1 = rowpos[2 * t + 1];
  float w0 = tokw[2 * t], w1 = tokw[2 * t + 1];
  float4 a0 = *(const float4*)&p0[(size_t)r0 * DDIM + d];
  float4 a1 = *(const float4*)&p1[(size_t)r0 * DDIM + d];
  float4 b0 = *(const float4*)&p0[(size_t)r1 * DDIM + d];
  float4 b1 = *(const float4*)&p1[(size_t)r1 * DDIM + d];
  float4 o;
  o.x = w0 * (a0.x + a1.x) + w1 * (b0.x + b1.x);
  o.y = w0 * (a0.y + a1.y) + w1 * (b0.y + b1.y);
  o.z = w0 * (a0.z + a1.z) + w1 * (b0.z + b1.z);
  o.w = w0 * (a0.w + a1.w) + w1 * (b0.w + b1.w);
  *(float4*)&out[(size_t)t * DDIM + d] = o;
}

extern "C" void kernel_launch(void* const* d_in, const int* in_sizes, int n_in,
                              void* d_out, int out_size, void* d_ws, size_t ws_size,
                              hipStream_t stream) {
  const float* x  = (const float*)d_in[0];
  const float* W1 = (const float*)d_in[1];
  const float* b1 = (const float*)d_in[2];
  const float* W2 = (const float*)d_in[3];
  const float* b2 = (const float*)d_in[4];
  const float* Wr = (const float*)d_in[5];
  const float* br = (const float*)d_in[6];
  float* out = (float*)d_out;

  if (ws_size < WS_NEED) return;

  char* ws = (char*)d_ws;
  int* ctrl            = (int*)(ws + OFF_CTRL);
  int* rowmap          = (int*)(ws + OFF_ROWMAP);
  int* rowpos          = (int*)(ws + OFF_ROWPOS);
  int* toke            = (int*)(ws + OFF_TOKE);
  float* tokw          = (float*)(ws + OFF_TOKW);
  unsigned short* xb   = (unsigned short*)(ws + OFF_XB);
  unsigned short* W1T  = (unsigned short*)(ws + OFF_W1T);
  unsigned short* W2T  = (unsigned short*)(ws + OFF_W2T);
  unsigned short* hbuf = (unsigned short*)(ws + OFF_H);
  float* pout          = (float*)(ws + OFF_PO);
  float* pout2         = (float*)(ws + OFF_W1T);  // aliases W1T — dead after GEMM1

  hipMemsetAsync(ws, 0, 256, stream);  // ctrl only; rowmap/rowpos fully written

  router_k<<<TT / 4, 256, 0, stream>>>(x, Wr, br, xb, ctrl, toke, tokw);
  scan_k<<<1, 64, 0, stream>>>(ctrl);
  assign_k<<<TT / 256, 256, 0, stream>>>(toke, ctrl, rowmap, rowpos);

  convT_k<<<dim3(HDIM / 64, DDIM / 64, NE), 256, 0, stream>>>(W1, W1T, DDIM, HDIM);
  convT_k<<<dim3(DDIM / 64, HDIM / 64, NE), 256, 0, stream>>>(W2, W2T, HDIM, DDIM);

  // GEMM1: M=rows(e), N=4096, K=1024; gathered A; gelu epilogue -> bf16 hbuf
  gemm_k<DDIM, DDIM, HDIM, true, true, false>
      <<<dim3(HDIM / 256, 32, NE), 512, 0, stream>>>(
      xb, W1T, ctrl, rowmap, b1, hbuf, nullptr, nullptr);
  // GEMM2: M=rows(e), N=1024, K=4096 split 2; f32 partials
  gemm_k<HDIM, HDIM / 2, DDIM, false, false, true>
      <<<dim3(DDIM / 256, 32, NE * 2), 512, 0, stream>>>(
      hbuf, W2T, ctrl, rowmap, b2, nullptr, pout, pout2);

  gather_k<<<TT, 256, 0, stream>>>(pout, pout2, rowpos, tokw, out);
}